// Round 1
// baseline (736.538 us; speedup 1.0000x reference)
//
#include <hip/hip_runtime.h>
#include <math.h>

#define BB 8
#define HO_ 152
#define WO_ 272
#define HW (HO_*WO_)        // 41344
#define MO_ 128
#define NID_ 537
#define EMB_SCALE 8.8871108f

// ws layout (floats): [0..7]=pos_l, [8..15]=neg_l, [16..23]=npos,
// [24..31]=reg_num, [32..39]=vis_num, [40..47]=id_sum(positive)
#define WS_PL   0
#define WS_NL   8
#define WS_NP   16
#define WS_REG  24
#define WS_VIS  32
#define WS_ID   40
#define WS_FLOATS 48

__device__ __forceinline__ float block_sum(float v, float* red) {
#pragma unroll
    for (int off = 32; off > 0; off >>= 1) v += __shfl_down(v, off, 64);
    int w = threadIdx.x >> 6, lane = threadIdx.x & 63;
    __syncthreads();
    if (lane == 0) red[w] = v;
    __syncthreads();
    return red[0] + red[1] + red[2] + red[3];
}

__device__ __forceinline__ float block_max(float v, float* red) {
#pragma unroll
    for (int off = 32; off > 0; off >>= 1) v = fmaxf(v, __shfl_down(v, off, 64));
    int w = threadIdx.x >> 6, lane = threadIdx.x & 63;
    __syncthreads();
    if (lane == 0) red[w] = v;
    __syncthreads();
    return fmaxf(fmaxf(red[0], red[1]), fmaxf(red[2], red[3]));
}

// ---------------- focal loss over full classification map ----------------
__global__ __launch_bounds__(256) void focal_kernel(const float* __restrict__ cls,
                                                    const float* __restrict__ hm,
                                                    float* __restrict__ ws) {
    int b = blockIdx.y;
    const float* x = cls + (size_t)b * HW;
    const float* g = hm + (size_t)b * HW;
    float pl = 0.f, nl = 0.f, np = 0.f;
    for (int i = blockIdx.x * blockDim.x + threadIdx.x; i < HW; i += gridDim.x * blockDim.x) {
        float p = 1.f / (1.f + expf(-x[i]));
        p = fminf(fmaxf(p, 1e-4f), 1.f - 1e-4f);
        float gt = g[i];
        if (gt == 1.0f) {
            float q = 1.f - p;
            pl += logf(p) * q * q;
            np += 1.f;
        } else {
            float w = 1.f - gt; w *= w; w *= w;          // (1-gt)^4
            nl += logf(1.f - p) * p * p * w;
        }
    }
    __shared__ float red[8];
    pl = block_sum(pl, red);
    nl = block_sum(nl, red);
    np = block_sum(np, red);
    if (threadIdx.x == 0) {
        atomicAdd(&ws[WS_PL + b], pl);
        atomicAdd(&ws[WS_NL + b], nl);
        atomicAdd(&ws[WS_NP + b], np);
    }
}

// ---------------- per-(b,m) row: reg L1, vis L1, 4x id loss ----------------
__global__ __launch_bounds__(256) void row_kernel(
    const float* __restrict__ regs, const float* __restrict__ viss,
    const float* __restrict__ id64, const float* __restrict__ id128,
    const float* __restrict__ id256, const float* __restrict__ idend,
    const float* __restrict__ wh, const float* __restrict__ v,
    const float* __restrict__ W64, const float* __restrict__ b64,
    const float* __restrict__ W128, const float* __restrict__ b128,
    const float* __restrict__ W256, const float* __restrict__ b256,
    const float* __restrict__ Wend, const float* __restrict__ bend,
    const int* __restrict__ ind, const int* __restrict__ mask,
    const int* __restrict__ ids, float* __restrict__ ws) {

    const int row = blockIdx.x;             // 0..1023
    const int b = row >> 7;
    if (mask[row] == 0) return;             // block-uniform; zero contribution
    const int pos = ind[row];
    const int t = threadIdx.x;

    __shared__ float fLds[256];
    __shared__ float logits[NID_];
    __shared__ float red[8];

    if (t == 0) {
        // regression L1 over 8 dims
        float s = 0.f;
        for (int c = 0; c < 8; ++c) {
            float p = regs[((size_t)(b * 8 + c)) * HW + pos];
            s += fabsf(p - wh[row * 8 + c]);
        }
        atomicAdd(&ws[WS_REG + b], s);
        // vis L1
        float x = viss[(size_t)b * HW + pos];
        float pv = 1.f / (1.f + expf(-x));
        pv = fminf(fmaxf(pv, 1e-4f), 1.f - 1e-4f);
        atomicAdd(&ws[WS_VIS + b], fabsf(pv - v[row]));
    }

    const float* F[4]  = {id64, id128, id256, idend};
    const float* W[4]  = {W64, W128, W256, Wend};
    const float* BS[4] = {b64, b128, b256, bend};
    const int    C4[4] = {64, 128, 256, 128};

    const int myid = ids[row];
    float picked_total = 0.f;

#pragma unroll 1
    for (int h = 0; h < 4; ++h) {
        const int C = C4[h];
        if (t < C) fLds[t] = F[h][((size_t)(b * C + t)) * HW + pos];
        __syncthreads();

        float sq = (t < C) ? fLds[t] * fLds[t] : 0.f;
        float sumsq = block_sum(sq, red);
        float scale = EMB_SCALE / fmaxf(sqrtf(sumsq), 1e-12f);

        const float4* f4 = (const float4*)fLds;
        const int nq = C >> 2;
        for (int n = t; n < NID_; n += 256) {
            const float4* wrow = (const float4*)(W[h] + (size_t)n * C);
            float dot = 0.f;
#pragma unroll 4
            for (int j = 0; j < nq; ++j) {
                float4 wv = wrow[j];
                float4 fv = f4[j];
                dot += wv.x * fv.x + wv.y * fv.y + wv.z * fv.z + wv.w * fv.w;
            }
            logits[n] = BS[h][n] + scale * dot;
        }
        __syncthreads();

        float lm = -INFINITY;
        for (int n = t; n < NID_; n += 256) lm = fmaxf(lm, logits[n]);
        float gmax = block_max(lm, red);

        float es = 0.f;
        for (int n = t; n < NID_; n += 256) es += expf(logits[n] - gmax);
        float ssum = block_sum(es, red);

        picked_total += logits[myid] - gmax - logf(ssum);
        __syncthreads();   // protect fLds/logits before next head
    }

    if (t == 0) atomicAdd(&ws[WS_ID + b], v[row] * picked_total);
}

// ---------------- finalize: per-batch losses -> 4 means ----------------
__global__ __launch_bounds__(256) void finalize_kernel(const int* __restrict__ mask,
                                                       const float* __restrict__ ws,
                                                       float* __restrict__ out) {
    int t = threadIdx.x;
    __shared__ float per[4][BB];
    if (t < BB) {
        int b = t;
        float cnt = 0.f;
        for (int m = 0; m < MO_; ++m) cnt += (float)mask[b * MO_ + m];
        float pl = ws[WS_PL + b], nl = ws[WS_NL + b], np = ws[WS_NP + b];
        per[0][b] = (np > 0.f) ? -(pl + nl) / fmaxf(np, 1.f) : -nl;
        per[1][b] = ws[WS_REG + b] / (cnt * 8.f + 1e-4f);
        per[2][b] = ws[WS_VIS + b] / (cnt * 1.f + 1e-4f);
        per[3][b] = -ws[WS_ID + b] / fmaxf(cnt, 1.f);
    }
    __syncthreads();
    if (t < 4) {
        float s = 0.f;
        for (int b = 0; b < BB; ++b) s += per[t][b];
        out[t] = s / (float)BB;
    }
}

extern "C" void kernel_launch(void* const* d_in, const int* in_sizes, int n_in,
                              void* d_out, int out_size, void* d_ws, size_t ws_size,
                              hipStream_t stream) {
    const float* cls   = (const float*)d_in[0];
    const float* regs  = (const float*)d_in[1];
    const float* viss  = (const float*)d_in[2];
    const float* id64  = (const float*)d_in[3];
    const float* id128 = (const float*)d_in[4];
    const float* id256 = (const float*)d_in[5];
    const float* idend = (const float*)d_in[6];
    const float* hm    = (const float*)d_in[7];
    const float* wh    = (const float*)d_in[8];
    const float* v     = (const float*)d_in[9];
    const float* W64   = (const float*)d_in[10];
    const float* b64   = (const float*)d_in[11];
    const float* W128  = (const float*)d_in[12];
    const float* b128  = (const float*)d_in[13];
    const float* W256  = (const float*)d_in[14];
    const float* b256  = (const float*)d_in[15];
    const float* Wend  = (const float*)d_in[16];
    const float* bend  = (const float*)d_in[17];
    // d_in[18]=s_det, d_in[19]=s_id : unused by the reference outputs
    const int* ind   = (const int*)d_in[20];
    const int* mask  = (const int*)d_in[21];
    const int* ids   = (const int*)d_in[22];

    float* ws  = (float*)d_ws;
    float* out = (float*)d_out;

    hipMemsetAsync(ws, 0, WS_FLOATS * sizeof(float), stream);

    focal_kernel<<<dim3(64, BB), 256, 0, stream>>>(cls, hm, ws);

    row_kernel<<<BB * MO_, 256, 0, stream>>>(
        regs, viss, id64, id128, id256, idend, wh, v,
        W64, b64, W128, b128, W256, b256, Wend, bend,
        ind, mask, ids, ws);

    finalize_kernel<<<1, 256, 0, stream>>>(mask, ws, out);
}

// Round 3
// 648.195 us; speedup vs baseline: 1.1363x; 1.1363x over previous
//
#include <hip/hip_runtime.h>
#include <math.h>

#define BB 8
#define HO_ 152
#define WO_ 272
#define HW 41344
#define MO_ 128
#define NID_ 537
#define NIDP 544
#define EMB_SCALE 8.8871108f

// ws layout (floats): [0..7]=pos_l, [8..15]=neg_l, [16..23]=npos,
// [24..31]=reg_num, [32..39]=vis_num, [40..47]=id_sum(positive)
#define WS_PL   0
#define WS_NL   8
#define WS_NP   16
#define WS_REG  24
#define WS_VIS  32
#define WS_ID   40
#define WS_FLOATS 48

// ---------------- wave-level reductions (width 64) ----------------
__device__ __forceinline__ float wsum(float v) {
#pragma unroll
    for (int o = 32; o > 0; o >>= 1) v += __shfl_xor(v, o, 64);
    return v;
}
__device__ __forceinline__ float wmax(float v) {
#pragma unroll
    for (int o = 32; o > 0; o >>= 1) v = fmaxf(v, __shfl_xor(v, o, 64));
    return v;
}

__device__ __forceinline__ float block_sum(float v, float* red) {
#pragma unroll
    for (int off = 32; off > 0; off >>= 1) v += __shfl_down(v, off, 64);
    int w = threadIdx.x >> 6, lane = threadIdx.x & 63;
    __syncthreads();
    if (lane == 0) red[w] = v;
    __syncthreads();
    return red[0] + red[1] + red[2] + red[3];
}

// ---------------- focal loss over full classification map ----------------
__global__ __launch_bounds__(256) void focal_kernel(const float* __restrict__ cls,
                                                    const float* __restrict__ hm,
                                                    float* __restrict__ ws) {
    const int b = blockIdx.y;
    const float4* x4 = (const float4*)(cls + (size_t)b * HW);
    const float4* g4 = (const float4*)(hm + (size_t)b * HW);
    float pl = 0.f, nl = 0.f, np = 0.f;
    const int n4 = HW / 4;   // 10336, exact
    for (int i = blockIdx.x * blockDim.x + threadIdx.x; i < n4; i += gridDim.x * blockDim.x) {
        float4 xv = x4[i], gv = g4[i];
        float xs[4] = {xv.x, xv.y, xv.z, xv.w};
        float gs[4] = {gv.x, gv.y, gv.z, gv.w};
#pragma unroll
        for (int k = 0; k < 4; ++k) {
            float p = 1.f / (1.f + expf(-xs[k]));
            p = fminf(fmaxf(p, 1e-4f), 1.f - 1e-4f);
            float gt = gs[k];
            if (gt == 1.0f) {
                float q = 1.f - p;
                pl += logf(p) * q * q;
                np += 1.f;
            } else {
                float w = 1.f - gt; w *= w; w *= w;     // (1-gt)^4
                nl += logf(1.f - p) * p * p * w;
            }
        }
    }
    __shared__ float red[4];
    pl = block_sum(pl, red);
    nl = block_sum(nl, red);
    np = block_sum(np, red);
    if (threadIdx.x == 0) {
        atomicAdd(&ws[WS_PL + b], pl);
        atomicAdd(&ws[WS_NL + b], nl);
        atomicAdd(&ws[WS_NP + b], np);
    }
}

// ---------------- reg L1 + vis L1, one thread per row ----------------
__global__ __launch_bounds__(256) void regvis_kernel(
    const float* __restrict__ regs, const float* __restrict__ viss,
    const float* __restrict__ wh, const float* __restrict__ v,
    const int* __restrict__ ind, const int* __restrict__ mask,
    float* __restrict__ ws) {
    const int row = blockIdx.x * 256 + threadIdx.x;    // grid 4 -> rows 0..1023
    const int b = row >> 7;                            // uniform within a wave
    const int l = threadIdx.x & 63;
    float sreg = 0.f, svis = 0.f;
    if (mask[row]) {
        const int pos = ind[row];
        const float* wr = wh + row * 8;
        float s = 0.f;
#pragma unroll
        for (int c = 0; c < 8; ++c)
            s += fabsf(regs[((size_t)(b * 8 + c)) * HW + pos] - wr[c]);
        sreg = s;
        float x = viss[(size_t)b * HW + pos];
        float pv = 1.f / (1.f + expf(-x));
        pv = fminf(fmaxf(pv, 1e-4f), 1.f - 1e-4f);
        svis = fabsf(pv - v[row]);
    }
    sreg = wsum(sreg);
    svis = wsum(svis);
    if (l == 0) {
        atomicAdd(&ws[WS_REG + b], sreg);
        atomicAdd(&ws[WS_VIS + b], svis);
    }
}

// ---------------- id loss: block = (4-row group, head) ----------------
__global__ __launch_bounds__(256) void idloss_kernel(
    const float* __restrict__ id64, const float* __restrict__ id128,
    const float* __restrict__ id256, const float* __restrict__ idend,
    const float* __restrict__ W64, const float* __restrict__ b64,
    const float* __restrict__ W128, const float* __restrict__ b128,
    const float* __restrict__ W256, const float* __restrict__ b256,
    const float* __restrict__ Wend, const float* __restrict__ bend,
    const float* __restrict__ v,
    const int* __restrict__ ind, const int* __restrict__ mask,
    const int* __restrict__ ids, float* __restrict__ ws) {

    const int g = blockIdx.x;       // 0..255 : rows 4g..4g+3
    const int h = blockIdx.y;       // 0..3   : head
    const int t = threadIdx.x;
    const int b = g >> 5;           // 32 groups per batch

    __shared__ int   sInd[4], sMsk[4], sId[4];
    __shared__ float sV[4], sSc[4];
    __shared__ float fLds[4][256];
    __shared__ float logits[4][NIDP];

    if (t < 4) {
        const int row = g * 4 + t;
        sInd[t] = ind[row]; sMsk[t] = mask[row];
        sId[t]  = ids[row]; sV[t]   = v[row];
    }
    __syncthreads();
    if (!(sMsk[0] | sMsk[1] | sMsk[2] | sMsk[3])) return;   // block-uniform

    const float* F; const float* W; const float* Bs; int C;
    switch (h) {
        case 0: F = id64;  W = W64;  Bs = b64;  C = 64;  break;
        case 1: F = id128; W = W128; Bs = b128; C = 128; break;
        case 2: F = id256; W = W256; Bs = b256; C = 256; break;
        default:F = idend; W = Wend; Bs = bend; C = 128; break;
    }

    // gather the 4 feature vectors
    if (t < C) {
#pragma unroll
        for (int r = 0; r < 4; ++r)
            fLds[r][t] = F[((size_t)(b * C + t)) * HW + sInd[r]];
    }
    __syncthreads();

    // per-wave norm of one row
    {
        const int w = t >> 6, l = t & 63;
        float s = 0.f;
        for (int j = l; j < C; j += 64) { float x = fLds[w][j]; s += x * x; }
        s = wsum(s);
        if (l == 0) sSc[w] = EMB_SCALE / fmaxf(sqrtf(s), 1e-12f);
    }
    __syncthreads();

    const float s0 = sSc[0], s1 = sSc[1], s2 = sSc[2], s3 = sSc[3];
    const float4* f0 = (const float4*)fLds[0];
    const float4* f1 = (const float4*)fLds[1];
    const float4* f2 = (const float4*)fLds[2];
    const float4* f3 = (const float4*)fLds[3];
    const int nq = C >> 2;

    for (int n = t; n < NID_; n += 256) {
        const float4* wr = (const float4*)(W + (size_t)n * C);
        float d0 = 0.f, d1 = 0.f, d2 = 0.f, d3 = 0.f;
#pragma unroll 4
        for (int j = 0; j < nq; ++j) {
            float4 wv = wr[j];
            float4 a0 = f0[j], a1 = f1[j], a2 = f2[j], a3 = f3[j];
            d0 += wv.x * a0.x + wv.y * a0.y + wv.z * a0.z + wv.w * a0.w;
            d1 += wv.x * a1.x + wv.y * a1.y + wv.z * a1.z + wv.w * a1.w;
            d2 += wv.x * a2.x + wv.y * a2.y + wv.z * a2.z + wv.w * a2.w;
            d3 += wv.x * a3.x + wv.y * a3.y + wv.z * a3.z + wv.w * a3.w;
        }
        const float bb = Bs[n];
        logits[0][n] = bb + s0 * d0;
        logits[1][n] = bb + s1 * d1;
        logits[2][n] = bb + s2 * d2;
        logits[3][n] = bb + s3 * d3;
    }
    __syncthreads();

    // per-wave softmax of one row
    {
        const int w = t >> 6, l = t & 63;
        if (sMsk[w]) {
            float m = -INFINITY;
            for (int n = l; n < NID_; n += 64) m = fmaxf(m, logits[w][n]);
            m = wmax(m);
            float e = 0.f;
            for (int n = l; n < NID_; n += 64) e += expf(logits[w][n] - m);
            e = wsum(e);
            if (l == 0)
                atomicAdd(&ws[WS_ID + b], sV[w] * (logits[w][sId[w]] - m - logf(e)));
        }
    }
}

// ---------------- finalize: per-batch losses -> 4 means ----------------
__global__ __launch_bounds__(256) void finalize_kernel(const int* __restrict__ mask,
                                                       const float* __restrict__ ws,
                                                       float* __restrict__ out) {
    int t = threadIdx.x;
    __shared__ float per[4][BB];
    if (t < BB) {
        int b = t;
        float cnt = 0.f;
        for (int m = 0; m < MO_; ++m) cnt += (float)mask[b * MO_ + m];
        float pl = ws[WS_PL + b], nl = ws[WS_NL + b], np = ws[WS_NP + b];
        per[0][b] = (np > 0.f) ? -(pl + nl) / fmaxf(np, 1.f) : -nl;
        per[1][b] = ws[WS_REG + b] / (cnt * 8.f + 1e-4f);
        per[2][b] = ws[WS_VIS + b] / (cnt * 1.f + 1e-4f);
        per[3][b] = -ws[WS_ID + b] / fmaxf(cnt, 1.f);
    }
    __syncthreads();
    if (t < 4) {
        float s = 0.f;
        for (int b = 0; b < BB; ++b) s += per[t][b];
        out[t] = s / (float)BB;
    }
}

extern "C" void kernel_launch(void* const* d_in, const int* in_sizes, int n_in,
                              void* d_out, int out_size, void* d_ws, size_t ws_size,
                              hipStream_t stream) {
    const float* cls   = (const float*)d_in[0];
    const float* regs  = (const float*)d_in[1];
    const float* viss  = (const float*)d_in[2];
    const float* id64  = (const float*)d_in[3];
    const float* id128 = (const float*)d_in[4];
    const float* id256 = (const float*)d_in[5];
    const float* idend = (const float*)d_in[6];
    const float* hm    = (const float*)d_in[7];
    const float* wh    = (const float*)d_in[8];
    const float* v     = (const float*)d_in[9];
    const float* W64   = (const float*)d_in[10];
    const float* b64   = (const float*)d_in[11];
    const float* W128  = (const float*)d_in[12];
    const float* b128  = (const float*)d_in[13];
    const float* W256  = (const float*)d_in[14];
    const float* b256  = (const float*)d_in[15];
    const float* Wend  = (const float*)d_in[16];
    const float* bend  = (const float*)d_in[17];
    // d_in[18]=s_det, d_in[19]=s_id : unused by the reference outputs
    const int* ind   = (const int*)d_in[20];
    const int* mask  = (const int*)d_in[21];
    const int* ids   = (const int*)d_in[22];

    float* ws  = (float*)d_ws;
    float* out = (float*)d_out;

    hipMemsetAsync(ws, 0, WS_FLOATS * sizeof(float), stream);

    focal_kernel<<<dim3(16, BB), 256, 0, stream>>>(cls, hm, ws);

    regvis_kernel<<<4, 256, 0, stream>>>(regs, viss, wh, v, ind, mask, ws);

    idloss_kernel<<<dim3(256, 4), 256, 0, stream>>>(
        id64, id128, id256, idend,
        W64, b64, W128, b128, W256, b256, Wend, bend,
        v, ind, mask, ids, ws);

    finalize_kernel<<<1, 256, 0, stream>>>(mask, ws, out);
}